// Round 1
// baseline (907.676 us; speedup 1.0000x reference)
//
#include <hip/hip_runtime.h>
#include <hip/hip_bf16.h>

#define NN 768
#define NSQ (768*768)
#define CS 384
#define CZ 128
#define HH 12
#define INF_ 1e5f
#define EPS_ 1e-8f
#define LN_EPS_ 1e-5f

typedef __attribute__((ext_vector_type(8))) short short8;
typedef __attribute__((ext_vector_type(4))) float floatx4;

// ---- workspace layout (float element offsets) ----
constexpr size_t OFF_SLN  = 0;                          // 768*384
constexpr size_t OFF_PROJ = OFF_SLN + (size_t)768*384;  // 768*1152 : [q 0..191 | k 192..383 | v 384..575 | qp 576..719 | kp 720..863 | vp 864..1151]
constexpr size_t OFF_QPG  = OFF_PROJ + (size_t)768*1152;// 768*144 (global-frame q points)
constexpr size_t OFF_KPG  = OFF_QPG + (size_t)768*144;  // 768*144
constexpr size_t OFF_VPG  = OFF_KPG + (size_t)768*144;  // 768*288
constexpr size_t OFF_WTBF = OFF_VPG + (size_t)768*288;  // 48*128 bf16 (ushort), padded to 4096 floats
constexpr size_t OFF_HW   = OFF_WTBF + 4096;            // 16
constexpr size_t OFF_ATT  = OFF_HW + 16;                // 12*NSQ : bias -> logits -> probs, layout [h][i][j]
constexpr size_t OFF_PZ   = OFF_ATT + (size_t)12*NSQ;   // NSQ*32 : pair_z [pair][c]
constexpr size_t OFF_OCAT = OFF_PZ + (size_t)NSQ*32;    // 768*960 : [o 0..191 | o_pair 192..575 | pt 576..863 | norm 864..959]
constexpr size_t OFF_PSUM = OFF_OCAT + (size_t)768*960; // 4*768*384 partial sums for final GEMM

__device__ __forceinline__ unsigned short f2bf(float f){
    unsigned int u = __float_as_uint(f);
    u = (u + 0x7fffu + ((u >> 16) & 1u)) >> 16;
    return (unsigned short)u;
}

// ---- K0: build bf16 W^T [48][128] (rows: 0..11 Wb cols, 12..43 Wdz cols, 44..47 zero) + softplus(head_weights)*sqrt(1/54)
__global__ __launch_bounds__(128) void k_prep(const float* __restrict__ Wb, const float* __restrict__ Wdz,
                                              const float* __restrict__ hwin, float* __restrict__ ws){
    unsigned short* wt = (unsigned short*)(ws + OFF_WTBF);
    float* hw = ws + OFF_HW;
    int bx = blockIdx.x, t = threadIdx.x;
    if (bx < 48){
        int o = bx, k = t;
        float v = 0.f;
        if (o < HH) v = Wb[k*HH + o];
        else if (o < HH + 32) v = Wdz[k*32 + (o - HH)];
        wt[o*128 + k] = f2bf(v);
    } else {
        if (t < HH){
            float x = hwin[t];
            hw[t] = log1pf(expf(x)) * sqrtf(1.0f/54.0f);
        }
    }
}

// ---- K1: LayerNorm(s) -> s_ln
__global__ __launch_bounds__(128) void k_lns(const float* __restrict__ s, const float* __restrict__ g,
                                             const float* __restrict__ b, float* __restrict__ ws){
    int i = blockIdx.x, t = threadIdx.x;
    const float* row = s + (size_t)i*CS;
    float x0 = row[t], x1 = row[t+128], x2 = row[t+256];
    float sum = x0+x1+x2, sq = x0*x0+x1*x1+x2*x2;
    for (int off = 32; off; off >>= 1){ sum += __shfl_down(sum, off, 64); sq += __shfl_down(sq, off, 64); }
    __shared__ float ls[2][2];
    int w = t >> 6;
    if ((t & 63) == 0){ ls[w][0] = sum; ls[w][1] = sq; }
    __syncthreads();
    sum = ls[0][0] + ls[1][0]; sq = ls[0][1] + ls[1][1];
    float mu = sum * (1.0f/CS);
    float var = sq * (1.0f/CS) - mu*mu;
    float rstd = rsqrtf(var + LN_EPS_);
    float* out = ws + OFF_SLN + (size_t)i*CS;
    out[t]     = (x0-mu)*rstd*g[t]     + b[t];
    out[t+128] = (x1-mu)*rstd*g[t+128] + b[t+128];
    out[t+256] = (x2-mu)*rstd*g[t+256] + b[t+256];
}

// ---- K2: all six projections, s_ln (768x384) @ W (384x1152) -> proj
__global__ __launch_bounds__(256) void k_proj(const float* __restrict__ Wq, const float* __restrict__ Wk,
                                              const float* __restrict__ Wv, const float* __restrict__ Wqp,
                                              const float* __restrict__ Wkp, const float* __restrict__ Wvp,
                                              float* __restrict__ ws){
    __shared__ float slds[16][CS];
    const float* sln = ws + OFF_SLN;
    int rt = blockIdx.x, ct = blockIdx.y, t = threadIdx.x;
    for (int ix = t; ix < 16*CS; ix += 256){
        int r = ix / CS, c = ix % CS;
        slds[r][c] = sln[(size_t)(rt*16 + r)*CS + c];
    }
    __syncthreads();
    int col = ct*128 + (t & 127);
    int rg = t >> 7;
    const float* wp; int stride;
    if      (col < 192){ wp = Wq  + col;       stride = 192; }
    else if (col < 384){ wp = Wk  + (col-192); stride = 192; }
    else if (col < 576){ wp = Wv  + (col-384); stride = 192; }
    else if (col < 720){ wp = Wqp + (col-576); stride = 144; }
    else if (col < 864){ wp = Wkp + (col-720); stride = 144; }
    else               { wp = Wvp + (col-864); stride = 288; }
    float acc[8] = {0,0,0,0,0,0,0,0};
    for (int k = 0; k < CS; k++){
        float w = wp[(size_t)k*stride];
        #pragma unroll
        for (int r = 0; r < 8; r++) acc[r] += slds[rg*8+r][k] * w;
    }
    float* proj = ws + OFF_PROJ;
    for (int r = 0; r < 8; r++) proj[(size_t)(rt*16 + rg*8 + r)*1152 + col] = acc[r];
}

// ---- K2b: transform raw points to global frame: R x + t
__global__ __launch_bounds__(192) void k_pts(const float* __restrict__ rot, const float* __restrict__ trans,
                                             float* __restrict__ ws){
    int i = blockIdx.x, p = threadIdx.x; // 192 points: 48 qp, 48 kp, 96 vp
    const float* proj = ws + OFF_PROJ + (size_t)i*1152;
    const float* src; float* dst;
    if (p < 48)      { src = proj + 576 + p*3;       dst = ws + OFF_QPG + (size_t)i*144 + p*3; }
    else if (p < 96) { src = proj + 720 + (p-48)*3;  dst = ws + OFF_KPG + (size_t)i*144 + (p-48)*3; }
    else             { src = proj + 864 + (p-96)*3;  dst = ws + OFF_VPG + (size_t)i*288 + (p-96)*3; }
    float x = src[0], y = src[1], z = src[2];
    const float* R = rot + (size_t)i*9;
    const float* T = trans + (size_t)i*3;
    dst[0] = R[0]*x + R[1]*y + R[2]*z + T[0];
    dst[1] = R[3]*x + R[4]*y + R[5]*z + T[1];
    dst[2] = R[6]*x + R[7]*y + R[8]*z + T[2];
}

// ---- K3: LN(z) then [Wb|Wdz] via bf16 MFMA. 64 pairs/block, 16 pairs/wave.
__global__ __launch_bounds__(256) void k_z(const float* __restrict__ z, const float* __restrict__ gz,
                                           const float* __restrict__ bz, float* __restrict__ ws){
    __shared__ unsigned short zlds[64][136]; // 64 rows x 128 bf16, +8 pad (b128-friendly)
    int t = threadIdx.x;
    int pb = blockIdx.x * 64;
    // phase 1: load 64x128 z, LN per row, store bf16 to LDS
    int r = t >> 2, seg = t & 3;
    const float* zr = z + (size_t)(pb + r)*128 + seg*32;
    float f[32];
    #pragma unroll
    for (int q = 0; q < 8; q++){
        floatx4 v = *(const floatx4*)(zr + q*4);
        f[q*4+0] = v[0]; f[q*4+1] = v[1]; f[q*4+2] = v[2]; f[q*4+3] = v[3];
    }
    float sum = 0.f, sq = 0.f;
    #pragma unroll
    for (int c = 0; c < 32; c++){ sum += f[c]; sq += f[c]*f[c]; }
    sum += __shfl_xor(sum, 1, 64); sum += __shfl_xor(sum, 2, 64);
    sq  += __shfl_xor(sq , 1, 64); sq  += __shfl_xor(sq , 2, 64);
    float mu = sum * (1.0f/128.0f);
    float var = sq * (1.0f/128.0f) - mu*mu;
    float rstd = rsqrtf(var + LN_EPS_);
    #pragma unroll
    for (int q = 0; q < 4; q++){
        short8 sv;
        #pragma unroll
        for (int j = 0; j < 8; j++){
            int c = q*8 + j;
            float zn = (f[c]-mu)*rstd*gz[seg*32+c] + bz[seg*32+c];
            sv[j] = (short)f2bf(zn);
        }
        *(short8*)&zlds[r][seg*32 + q*8] = sv;
    }
    __syncthreads();
    // phase 2: wave w handles rows w*16..w*16+15; D[pair][o] = zn . W[:,o]
    const unsigned short* wt = (const unsigned short*)(ws + OFF_WTBF);
    int lane = t & 63, wv = t >> 6;
    int m = lane & 15, quad = lane >> 4;
    short8 bfrag[3][4];
    #pragma unroll
    for (int ot = 0; ot < 3; ot++)
        #pragma unroll
        for (int ks = 0; ks < 4; ks++){
            int o = ot*16 + m;
            bfrag[ot][ks] = *(const short8*)(wt + o*128 + ks*32 + quad*8);
        }
    floatx4 acc[3] = {{0.f,0.f,0.f,0.f},{0.f,0.f,0.f,0.f},{0.f,0.f,0.f,0.f}};
    int rbase = wv*16;
    #pragma unroll
    for (int ks = 0; ks < 4; ks++){
        short8 a = *(const short8*)&zlds[rbase + m][ks*32 + quad*8];
        acc[0] = __builtin_amdgcn_mfma_f32_16x16x32_bf16(a, bfrag[0][ks], acc[0], 0, 0, 0);
        acc[1] = __builtin_amdgcn_mfma_f32_16x16x32_bf16(a, bfrag[1][ks], acc[1], 0, 0, 0);
        acc[2] = __builtin_amdgcn_mfma_f32_16x16x32_bf16(a, bfrag[2][ks], acc[2], 0, 0, 0);
    }
    float* bias = ws + OFF_ATT;
    float* pz   = ws + OFF_PZ;
    #pragma unroll
    for (int ot = 0; ot < 3; ot++){
        int o = ot*16 + m;
        #pragma unroll
        for (int rg = 0; rg < 4; rg++){
            int pair = pb + rbase + quad*4 + rg;   // C/D: col=lane&15, row=(lane>>4)*4+reg
            float val = acc[ot][rg];
            if (o < HH)      bias[(size_t)o*NSQ + pair] = val;
            else if (o < 44) pz[(size_t)pair*32 + (o - HH)] = val;
        }
    }
}

// ---- K4: logits = qk*sqrt(1/48) + sqrt(1/3)*(bias+mask) - 0.5*hw*sum d2 ; in-place over bias buffer
__global__ __launch_bounds__(256) void k_logits(const float* __restrict__ smask, const int* __restrict__ idx,
                                                float* __restrict__ ws){
    __shared__ float qlds[8][336];   // [q 0..191 | qp_g 192..335]
    __shared__ float klds[32][337];  // [k 0..191 | kp_g 192..335]
    int it = blockIdx.x, jt = blockIdx.y, t = threadIdx.x;
    const float* proj = ws + OFF_PROJ;
    const float* qpg  = ws + OFF_QPG;
    const float* kpg  = ws + OFF_KPG;
    const float* hw   = ws + OFF_HW;
    float* att = ws + OFF_ATT;
    for (int ix = t; ix < 8*336; ix += 256){
        int r = ix / 336, c = ix % 336;
        int i = it*8 + r;
        qlds[r][c] = (c < 192) ? proj[(size_t)i*1152 + c] : qpg[(size_t)i*144 + (c - 192)];
    }
    for (int ix = t; ix < 32*336; ix += 256){
        int r = ix / 336, c = ix % 336;
        int j = jt*32 + r;
        klds[r][c] = (c < 192) ? proj[(size_t)j*1152 + 192 + c] : kpg[(size_t)j*144 + (c - 192)];
    }
    __syncthreads();
    int jl = t & 31, grp = t >> 5;
    int i = it*8 + grp, j = jt*32 + jl;
    int ires = idx[i], jres = idx[j];
    float mterm = INF_ * (smask[ires]*smask[jres] - 1.0f);
    const float S1 = 0.14433756729740643f;  // sqrt(1/48)
    const float S2 = 0.57735026918962576f;  // sqrt(1/3)
    for (int h = 0; h < HH; h++){
        float qk = 0.f;
        #pragma unroll
        for (int c = 0; c < 16; c++) qk += qlds[grp][h*16+c] * klds[jl][h*16+c];
        float d2 = 0.f;
        #pragma unroll
        for (int pd = 0; pd < 12; pd++){
            float dd = qlds[grp][192 + h*12 + pd] - klds[jl][192 + h*12 + pd];
            d2 += dd*dd;
        }
        float bv = att[(size_t)h*NSQ + (size_t)ires*NN + jres];
        float lg = qk*S1 + S2*(bv + mterm) - 0.5f*hw[h]*d2;
        att[(size_t)h*NSQ + (size_t)i*NN + j] = lg;
    }
}

// ---- K4c: softmax over j per (h,i), in place
__global__ __launch_bounds__(256) void k_softmax(float* __restrict__ ws){
    int b = blockIdx.x, t = threadIdx.x;
    int h = b / NN, i = b % NN;
    float* row = ws + OFF_ATT + (size_t)h*NSQ + (size_t)i*NN;
    float x0 = row[t], x1 = row[t+256], x2 = row[t+512];
    float mx = fmaxf(x0, fmaxf(x1, x2));
    for (int off = 32; off; off >>= 1) mx = fmaxf(mx, __shfl_down(mx, off, 64));
    __shared__ float lsm[4];
    __shared__ float lss[4];
    if ((t & 63) == 0) lsm[t >> 6] = mx;
    __syncthreads();
    mx = fmaxf(fmaxf(lsm[0], lsm[1]), fmaxf(lsm[2], lsm[3]));
    float e0 = expf(x0-mx), e1 = expf(x1-mx), e2 = expf(x2-mx);
    float s = e0 + e1 + e2;
    for (int off = 32; off; off >>= 1) s += __shfl_down(s, off, 64);
    if ((t & 63) == 0) lss[t >> 6] = s;
    __syncthreads();
    s = lss[0] + lss[1] + lss[2] + lss[3];
    float inv = 1.0f / s;
    row[t] = e0*inv; row[t+256] = e1*inv; row[t+512] = e2*inv;
}

// ---- K5: o and o_pt(global) per head: P_h(768x768) x [v|vp](768x40)
__global__ __launch_bounds__(256) void k_ov(float* __restrict__ ws){
    __shared__ float wlds[128][41];
    __shared__ float plds[32][128];
    int h = blockIdx.x, it = blockIdx.y, t = threadIdx.x;
    const float* proj = ws + OFF_PROJ;
    const float* vpg  = ws + OFF_VPG;
    const float* att  = ws + OFF_ATT + (size_t)h*NSQ;
    int c = t & 63, isub = t >> 6;
    float acc[8] = {0,0,0,0,0,0,0,0};
    for (int jt = 0; jt < 6; jt++){
        __syncthreads();
        for (int ix = t; ix < 128*40; ix += 256){
            int jj = ix / 40, cc = ix % 40;
            int j = jt*128 + jj;
            wlds[jj][cc] = (cc < 16) ? proj[(size_t)j*1152 + 384 + h*16 + cc]
                                     : vpg[(size_t)j*288 + h*24 + (cc - 16)];
        }
        for (int ix = t; ix < 32*128; ix += 256){
            int rr = ix >> 7, jj = ix & 127;
            plds[rr][jj] = att[(size_t)(it*32 + rr)*NN + jt*128 + jj];
        }
        __syncthreads();
        if (c < 40){
            for (int jj = 0; jj < 128; jj++){
                float w = wlds[jj][c];
                #pragma unroll
                for (int rr = 0; rr < 8; rr++) acc[rr] += plds[isub*8+rr][jj] * w;
            }
        }
    }
    if (c < 40){
        float* ocat = ws + OFF_OCAT;
        int col = (c < 16) ? (h*16 + c) : (576 + h*24 + (c - 16));
        for (int rr = 0; rr < 8; rr++){
            int i = it*32 + isub*8 + rr;
            ocat[(size_t)i*960 + col] = acc[rr];
        }
    }
}

// ---- K6: o_pair[i][h][c] = sum_j p[h][i][j] * pair_z[idx_i*N+idx_j][c]
__global__ __launch_bounds__(256) void k_opair(const int* __restrict__ idx, float* __restrict__ ws){
    __shared__ float pzlds[128][33];
    __shared__ float plds[12][129];
    int i = blockIdx.x, t = threadIdx.x;
    int ires = idx[i];
    const float* pz  = ws + OFF_PZ;
    const float* att = ws + OFF_ATT;
    int h0 = t >> 5, c0 = t & 31;            // h0 in 0..7
    int h1 = (t + 256) >> 5, c1 = c0;        // h1 in 8..15 (valid if <12)
    float acc0 = 0.f, acc1 = 0.f;
    for (int jt = 0; jt < 6; jt++){
        __syncthreads();
        for (int ix = t; ix < 128*32; ix += 256){
            int jj = ix >> 5, cc = ix & 31;
            int jres = idx[jt*128 + jj];
            pzlds[jj][cc] = pz[((size_t)ires*NN + jres)*32 + cc];
        }
        for (int ix = t; ix < 12*128; ix += 256){
            int hh = ix >> 7, jj = ix & 127;
            plds[hh][jj] = att[(size_t)hh*NSQ + (size_t)i*NN + jt*128 + jj];
        }
        __syncthreads();
        for (int jj = 0; jj < 128; jj++){
            acc0 += plds[h0][jj] * pzlds[jj][c0];
            if (h1 < HH) acc1 += plds[h1][jj] * pzlds[jj][c1];
        }
    }
    float* oc = ws + OFF_OCAT + (size_t)i*960 + 192;
    oc[h0*32 + c0] = acc0;
    if (h1 < HH) oc[h1*32 + c1] = acc1;
}

// ---- K6b: o_pt -> local frame R^T(x-t), plus norms
__global__ __launch_bounds__(96) void k_ptfin(const float* __restrict__ rot, const float* __restrict__ trans,
                                              float* __restrict__ ws){
    int i = blockIdx.x, p = threadIdx.x; // 96 points
    float* base = ws + OFF_OCAT + (size_t)i*960;
    float* pt = base + 576 + p*3;
    float x = pt[0] - trans[i*3+0];
    float y = pt[1] - trans[i*3+1];
    float z = pt[2] - trans[i*3+2];
    const float* R = rot + (size_t)i*9;
    float lx = R[0]*x + R[3]*y + R[6]*z;
    float ly = R[1]*x + R[4]*y + R[7]*z;
    float lz = R[2]*x + R[5]*y + R[8]*z;
    pt[0] = lx; pt[1] = ly; pt[2] = lz;
    base[864 + p] = sqrtf(lx*lx + ly*ly + lz*lz + EPS_);
}

// ---- K7: out = ocat(768x960) @ [Wout;Woutb;Woutpts](960x384), split over 4 k-chunks
__global__ __launch_bounds__(256) void k_out(const float* __restrict__ Wout, const float* __restrict__ Woutb,
                                             const float* __restrict__ Woutp, float* __restrict__ ws){
    __shared__ float olds[32][241];
    int it = blockIdx.x, ct = blockIdx.y, kc = blockIdx.z, t = threadIdx.x;
    const float* ocat = ws + OFF_OCAT;
    for (int ix = t; ix < 32*240; ix += 256){
        int r = ix / 240, kk = ix % 240;
        olds[r][kk] = ocat[(size_t)(it*32 + r)*960 + kc*240 + kk];
    }
    __syncthreads();
    int c = ct*128 + (t & 127);
    int ig = t >> 7;
    float acc[16] = {0,0,0,0,0,0,0,0,0,0,0,0,0,0,0,0};
    for (int kk = 0; kk < 240; kk++){
        int k = kc*240 + kk;
        const float* wrow = (k < 192) ? (Wout  + (size_t)k*CS)
                          : (k < 576) ? (Woutb + (size_t)(k-192)*CS)
                                      : (Woutp + (size_t)(k-576)*CS);
        float w = wrow[c];
        #pragma unroll
        for (int r = 0; r < 16; r++) acc[r] += olds[ig*16 + r][kk] * w;
    }
    float* psum = ws + OFF_PSUM + (size_t)kc*(768*384);
    for (int r = 0; r < 16; r++){
        int i = it*32 + ig*16 + r;
        psum[(size_t)i*CS + c] = acc[r];
    }
}

// ---- K7b: reduce 4 partial sums -> d_out
__global__ __launch_bounds__(256) void k_red(const float* __restrict__ ws, float* __restrict__ out){
    int e = blockIdx.x*256 + threadIdx.x;
    const float* ps = ws + OFF_PSUM;
    out[e] = ps[e] + ps[294912 + e] + ps[2*294912 + e] + ps[3*294912 + e];
}

extern "C" void kernel_launch(void* const* d_in, const int* in_sizes, int n_in,
                              void* d_out, int out_size, void* d_ws, size_t ws_size,
                              hipStream_t stream){
    const float* s     = (const float*)d_in[0];
    const float* z     = (const float*)d_in[1];
    const float* rot   = (const float*)d_in[2];
    const float* trans = (const float*)d_in[3];
    const float* smask = (const float*)d_in[4];
    const float* gs    = (const float*)d_in[5];
    const float* bs    = (const float*)d_in[6];
    const float* gz    = (const float*)d_in[7];
    const float* bz    = (const float*)d_in[8];
    const float* Wq    = (const float*)d_in[9];
    const float* Wk    = (const float*)d_in[10];
    const float* Wv    = (const float*)d_in[11];
    const float* Wqp   = (const float*)d_in[12];
    const float* Wkp   = (const float*)d_in[13];
    const float* Wvp   = (const float*)d_in[14];
    const float* Wb    = (const float*)d_in[15];
    const float* Wdz   = (const float*)d_in[16];
    const float* hwin  = (const float*)d_in[17];
    const float* Wout  = (const float*)d_in[18];
    const float* Woutb = (const float*)d_in[19];
    const float* Woutp = (const float*)d_in[20];
    const int*   idx   = (const int*)d_in[21];
    float* ws  = (float*)d_ws;
    float* out = (float*)d_out;

    k_prep   <<<49, 128, 0, stream>>>(Wb, Wdz, hwin, ws);
    k_lns    <<<768, 128, 0, stream>>>(s, gs, bs, ws);
    k_proj   <<<dim3(48, 9), 256, 0, stream>>>(Wq, Wk, Wv, Wqp, Wkp, Wvp, ws);
    k_pts    <<<768, 192, 0, stream>>>(rot, trans, ws);
    k_z      <<<9216, 256, 0, stream>>>(z, gz, bz, ws);
    k_logits <<<dim3(96, 24), 256, 0, stream>>>(smask, idx, ws);
    k_softmax<<<9216, 256, 0, stream>>>(ws);
    k_ov     <<<dim3(12, 24), 256, 0, stream>>>(ws);
    k_opair  <<<768, 256, 0, stream>>>(idx, ws);
    k_ptfin  <<<768, 96, 0, stream>>>(rot, trans, ws);
    k_out    <<<dim3(24, 3, 4), 256, 0, stream>>>(Wout, Woutb, Woutp, ws);
    k_red    <<<1152, 256, 0, stream>>>(ws, out);
}

// Round 2
// 861.741 us; speedup vs baseline: 1.0533x; 1.0533x over previous
//
#include <hip/hip_runtime.h>
#include <hip/hip_bf16.h>

#define NN 768
#define NSQ (768*768)
#define CS 384
#define CZ 128
#define HH 12
#define INF_ 1e5f
#define EPS_ 1e-8f
#define LN_EPS_ 1e-5f

typedef __attribute__((ext_vector_type(8))) short short8;
typedef __attribute__((ext_vector_type(4))) short short4_t;
typedef __attribute__((ext_vector_type(4))) float floatx4;

// ---- workspace layout (float element offsets) ----
constexpr size_t OFF_SLN  = 0;                          // 768*384
constexpr size_t OFF_PROJ = OFF_SLN + (size_t)768*384;  // 768*1152 : [q|k|v|qp|kp|vp]
constexpr size_t OFF_QPG  = OFF_PROJ + (size_t)768*1152;// 768*144
constexpr size_t OFF_KPG  = OFF_QPG + (size_t)768*144;  // 768*144
constexpr size_t OFF_VPG  = OFF_KPG + (size_t)768*144;  // 768*288
constexpr size_t OFF_WTBF = OFF_VPG + (size_t)768*288;  // 48*128 bf16
constexpr size_t OFF_HW   = OFF_WTBF + 4096;            // 16
constexpr size_t OFF_ATT  = OFF_HW + 16;                // 12*NSQ
constexpr size_t OFF_PZ   = OFF_ATT + (size_t)12*NSQ;   // NSQ*32
constexpr size_t OFF_OCAT = OFF_PZ + (size_t)NSQ*32;    // 768*960
constexpr size_t OFF_PSUM = OFF_OCAT + (size_t)768*960; // 4*768*384

__device__ __forceinline__ unsigned short f2bf(float f){
    unsigned int u = __float_as_uint(f);
    u = (u + 0x7fffu + ((u >> 16) & 1u)) >> 16;
    return (unsigned short)u;
}

// ---- K0: bf16 W^T [48][128] + softplus(head_weights)*sqrt(1/54)
__global__ __launch_bounds__(128) void k_prep(const float* __restrict__ Wb, const float* __restrict__ Wdz,
                                              const float* __restrict__ hwin, float* __restrict__ ws){
    unsigned short* wt = (unsigned short*)(ws + OFF_WTBF);
    float* hw = ws + OFF_HW;
    int bx = blockIdx.x, t = threadIdx.x;
    if (bx < 48){
        int o = bx, k = t;
        float v = 0.f;
        if (o < HH) v = Wb[k*HH + o];
        else if (o < HH + 32) v = Wdz[k*32 + (o - HH)];
        wt[o*128 + k] = f2bf(v);
    } else {
        if (t < HH){
            float x = hwin[t];
            hw[t] = log1pf(expf(x)) * sqrtf(1.0f/54.0f);
        }
    }
}

// ---- zero ocat (atomics target)
__global__ __launch_bounds__(256) void k_zero(float* __restrict__ ws){
    ws[OFF_OCAT + (size_t)blockIdx.x*256 + threadIdx.x] = 0.f;
}

// ---- K1: LayerNorm(s)
__global__ __launch_bounds__(128) void k_lns(const float* __restrict__ s, const float* __restrict__ g,
                                             const float* __restrict__ b, float* __restrict__ ws){
    int i = blockIdx.x, t = threadIdx.x;
    const float* row = s + (size_t)i*CS;
    float x0 = row[t], x1 = row[t+128], x2 = row[t+256];
    float sum = x0+x1+x2, sq = x0*x0+x1*x1+x2*x2;
    for (int off = 32; off; off >>= 1){ sum += __shfl_down(sum, off, 64); sq += __shfl_down(sq, off, 64); }
    __shared__ float ls[2][2];
    int w = t >> 6;
    if ((t & 63) == 0){ ls[w][0] = sum; ls[w][1] = sq; }
    __syncthreads();
    sum = ls[0][0] + ls[1][0]; sq = ls[0][1] + ls[1][1];
    float mu = sum * (1.0f/CS);
    float var = sq * (1.0f/CS) - mu*mu;
    float rstd = rsqrtf(var + LN_EPS_);
    float* out = ws + OFF_SLN + (size_t)i*CS;
    out[t]     = (x0-mu)*rstd*g[t]     + b[t];
    out[t+128] = (x1-mu)*rstd*g[t+128] + b[t+128];
    out[t+256] = (x2-mu)*rstd*g[t+256] + b[t+256];
}

// ---- K2: projections, s_ln (768x384) @ W (384x1152)
__global__ __launch_bounds__(256) void k_proj(const float* __restrict__ Wq, const float* __restrict__ Wk,
                                              const float* __restrict__ Wv, const float* __restrict__ Wqp,
                                              const float* __restrict__ Wkp, const float* __restrict__ Wvp,
                                              float* __restrict__ ws){
    __shared__ float slds[16][CS];
    const float* sln = ws + OFF_SLN;
    int rt = blockIdx.x, ct = blockIdx.y, t = threadIdx.x;
    for (int ix = t; ix < 16*CS; ix += 256){
        int r = ix / CS, c = ix % CS;
        slds[r][c] = sln[(size_t)(rt*16 + r)*CS + c];
    }
    __syncthreads();
    int col = ct*128 + (t & 127);
    int rg = t >> 7;
    const float* wp; int stride;
    if      (col < 192){ wp = Wq  + col;       stride = 192; }
    else if (col < 384){ wp = Wk  + (col-192); stride = 192; }
    else if (col < 576){ wp = Wv  + (col-384); stride = 192; }
    else if (col < 720){ wp = Wqp + (col-576); stride = 144; }
    else if (col < 864){ wp = Wkp + (col-720); stride = 144; }
    else               { wp = Wvp + (col-864); stride = 288; }
    float acc[8] = {0,0,0,0,0,0,0,0};
    for (int k = 0; k < CS; k += 4){
        float w0 = wp[(size_t)k*stride];
        float w1 = wp[(size_t)(k+1)*stride];
        float w2 = wp[(size_t)(k+2)*stride];
        float w3 = wp[(size_t)(k+3)*stride];
        #pragma unroll
        for (int r = 0; r < 8; r++){
            floatx4 sv = *(const floatx4*)&slds[rg*8+r][k];
            acc[r] += sv[0]*w0 + sv[1]*w1 + sv[2]*w2 + sv[3]*w3;
        }
    }
    float* proj = ws + OFF_PROJ;
    for (int r = 0; r < 8; r++) proj[(size_t)(rt*16 + rg*8 + r)*1152 + col] = acc[r];
}

// ---- K2b: points to global frame
__global__ __launch_bounds__(192) void k_pts(const float* __restrict__ rot, const float* __restrict__ trans,
                                             float* __restrict__ ws){
    int i = blockIdx.x, p = threadIdx.x;
    const float* proj = ws + OFF_PROJ + (size_t)i*1152;
    const float* src; float* dst;
    if (p < 48)      { src = proj + 576 + p*3;       dst = ws + OFF_QPG + (size_t)i*144 + p*3; }
    else if (p < 96) { src = proj + 720 + (p-48)*3;  dst = ws + OFF_KPG + (size_t)i*144 + (p-48)*3; }
    else             { src = proj + 864 + (p-96)*3;  dst = ws + OFF_VPG + (size_t)i*288 + (p-96)*3; }
    float x = src[0], y = src[1], z = src[2];
    const float* R = rot + (size_t)i*9;
    const float* T = trans + (size_t)i*3;
    dst[0] = R[0]*x + R[1]*y + R[2]*z + T[0];
    dst[1] = R[3]*x + R[4]*y + R[5]*z + T[1];
    dst[2] = R[6]*x + R[7]*y + R[8]*z + T[2];
}

// ---- K3: LN(z) + [Wb|Wdz] via bf16 MFMA, coalesced loads
__global__ __launch_bounds__(256) void k_z(const float* __restrict__ z, const float* __restrict__ gz,
                                           const float* __restrict__ bz, float* __restrict__ ws){
    __shared__ unsigned short zlds[64][136];
    int t = threadIdx.x;
    int pb = blockIdx.x * 64;
    int lane32 = t & 31;
    int col = lane32 * 4;
    floatx4 g4 = *(const floatx4*)(gz + col);
    floatx4 b4 = *(const floatx4*)(bz + col);
    const float* zbase = z + (size_t)pb * 128;
    #pragma unroll
    for (int g = 0; g < 8; g++){
        int row = g*8 + (t >> 5);
        floatx4 v = *(const floatx4*)(zbase + (size_t)g*1024 + (size_t)t*4);  // coalesced: 4KB/256thr
        float sum = v[0]+v[1]+v[2]+v[3];
        float sq  = v[0]*v[0]+v[1]*v[1]+v[2]*v[2]+v[3]*v[3];
        #pragma unroll
        for (int off = 1; off <= 16; off <<= 1){
            sum += __shfl_xor(sum, off, 64);
            sq  += __shfl_xor(sq , off, 64);
        }
        float mu = sum * (1.0f/128.0f);
        float rstd = rsqrtf(sq*(1.0f/128.0f) - mu*mu + LN_EPS_);
        short4_t sv;
        sv[0] = (short)f2bf((v[0]-mu)*rstd*g4[0] + b4[0]);
        sv[1] = (short)f2bf((v[1]-mu)*rstd*g4[1] + b4[1]);
        sv[2] = (short)f2bf((v[2]-mu)*rstd*g4[2] + b4[2]);
        sv[3] = (short)f2bf((v[3]-mu)*rstd*g4[3] + b4[3]);
        *(short4_t*)&zlds[row][col] = sv;
    }
    __syncthreads();
    // MFMA phase: wave wv handles rows wv*16..+15
    const unsigned short* wt = (const unsigned short*)(ws + OFF_WTBF);
    int lane = t & 63, wv = t >> 6;
    int m = lane & 15, quad = lane >> 4;
    short8 bfrag[3][4];
    #pragma unroll
    for (int ot = 0; ot < 3; ot++)
        #pragma unroll
        for (int ks = 0; ks < 4; ks++){
            int o = ot*16 + m;
            bfrag[ot][ks] = *(const short8*)(wt + o*128 + ks*32 + quad*8);
        }
    floatx4 acc[3] = {{0.f,0.f,0.f,0.f},{0.f,0.f,0.f,0.f},{0.f,0.f,0.f,0.f}};
    int rbase = wv*16;
    #pragma unroll
    for (int ks = 0; ks < 4; ks++){
        short8 a = *(const short8*)&zlds[rbase + m][ks*32 + quad*8];
        acc[0] = __builtin_amdgcn_mfma_f32_16x16x32_bf16(a, bfrag[0][ks], acc[0], 0, 0, 0);
        acc[1] = __builtin_amdgcn_mfma_f32_16x16x32_bf16(a, bfrag[1][ks], acc[1], 0, 0, 0);
        acc[2] = __builtin_amdgcn_mfma_f32_16x16x32_bf16(a, bfrag[2][ks], acc[2], 0, 0, 0);
    }
    float* bias = ws + OFF_ATT;
    float* pz   = ws + OFF_PZ;
    #pragma unroll
    for (int ot = 0; ot < 3; ot++){
        int o = ot*16 + m;
        #pragma unroll
        for (int rg = 0; rg < 4; rg++){
            int pair = pb + rbase + quad*4 + rg;
            float val = acc[ot][rg];
            if (o < HH)      bias[(size_t)o*NSQ + pair] = val;
            else if (o < 44) pz[(size_t)pair*32 + (o - HH)] = val;
        }
    }
}

// ---- K4: logits (in place over bias buffer)
__global__ __launch_bounds__(256) void k_logits(const float* __restrict__ smask, const int* __restrict__ idx,
                                                float* __restrict__ ws){
    __shared__ float qlds[8][336];
    __shared__ float klds[32][340];
    int it = blockIdx.x, jt = blockIdx.y, t = threadIdx.x;
    const float* proj = ws + OFF_PROJ;
    const float* qpg  = ws + OFF_QPG;
    const float* kpg  = ws + OFF_KPG;
    const float* hw   = ws + OFF_HW;
    float* att = ws + OFF_ATT;
    for (int ix = t; ix < 8*336; ix += 256){
        int r = ix / 336, c = ix % 336;
        int i = it*8 + r;
        qlds[r][c] = (c < 192) ? proj[(size_t)i*1152 + c] : qpg[(size_t)i*144 + (c - 192)];
    }
    for (int ix = t; ix < 32*336; ix += 256){
        int r = ix / 336, c = ix % 336;
        int j = jt*32 + r;
        klds[r][c] = (c < 192) ? proj[(size_t)j*1152 + 192 + c] : kpg[(size_t)j*144 + (c - 192)];
    }
    __syncthreads();
    int jl = t & 31, grp = t >> 5;
    int i = it*8 + grp, j = jt*32 + jl;
    int ires = idx[i], jres = idx[j];
    float mterm = INF_ * (smask[ires]*smask[jres] - 1.0f);
    const float S1 = 0.14433756729740643f;
    const float S2 = 0.57735026918962576f;
    for (int h = 0; h < HH; h++){
        float qk = 0.f;
        #pragma unroll
        for (int c4 = 0; c4 < 4; c4++){
            floatx4 qv = *(const floatx4*)&qlds[grp][h*16 + c4*4];
            floatx4 kv = *(const floatx4*)&klds[jl][h*16 + c4*4];
            qk += qv[0]*kv[0] + qv[1]*kv[1] + qv[2]*kv[2] + qv[3]*kv[3];
        }
        float d2 = 0.f;
        #pragma unroll
        for (int p4 = 0; p4 < 3; p4++){
            floatx4 qv = *(const floatx4*)&qlds[grp][192 + h*12 + p4*4];
            floatx4 kv = *(const floatx4*)&klds[jl][192 + h*12 + p4*4];
            float d0 = qv[0]-kv[0], d1 = qv[1]-kv[1], d2_ = qv[2]-kv[2], d3 = qv[3]-kv[3];
            d2 += d0*d0 + d1*d1 + d2_*d2_ + d3*d3;
        }
        float bv = att[(size_t)h*NSQ + (size_t)ires*NN + jres];
        float lg = qk*S1 + S2*(bv + mterm) - 0.5f*hw[h]*d2;
        att[(size_t)h*NSQ + (size_t)i*NN + j] = lg;
    }
}

// ---- K4c: softmax over j, float4
__global__ __launch_bounds__(192) void k_softmax(float* __restrict__ ws){
    int b = blockIdx.x, t = threadIdx.x;
    float* row = ws + OFF_ATT + (size_t)b*NN;
    floatx4 v = *(floatx4*)(row + t*4);
    float mx = fmaxf(fmaxf(v[0],v[1]), fmaxf(v[2],v[3]));
    for (int off = 32; off; off >>= 1) mx = fmaxf(mx, __shfl_xor(mx, off, 64));
    __shared__ float lsm[3];
    __shared__ float lss[3];
    int w = t >> 6;
    if ((t & 63) == 0) lsm[w] = mx;
    __syncthreads();
    mx = fmaxf(fmaxf(lsm[0], lsm[1]), lsm[2]);
    floatx4 e;
    e[0] = expf(v[0]-mx); e[1] = expf(v[1]-mx); e[2] = expf(v[2]-mx); e[3] = expf(v[3]-mx);
    float s = e[0]+e[1]+e[2]+e[3];
    for (int off = 32; off; off >>= 1) s += __shfl_xor(s, off, 64);
    if ((t & 63) == 0) lss[w] = s;
    __syncthreads();
    s = lss[0] + lss[1] + lss[2];
    float inv = 1.0f / s;
    e[0] *= inv; e[1] *= inv; e[2] *= inv; e[3] *= inv;
    *(floatx4*)(row + t*4) = e;
}

// ---- K5: o and o_pt(global), j-split x3, atomic accumulate
__global__ __launch_bounds__(256) void k_ov(float* __restrict__ ws){
    __shared__ float wlds[128][41];
    __shared__ float plds[32][128];
    int h = blockIdx.x, it = blockIdx.y, zs = blockIdx.z, t = threadIdx.x;
    const float* proj = ws + OFF_PROJ;
    const float* vpg  = ws + OFF_VPG;
    const float* att  = ws + OFF_ATT + (size_t)h*NSQ;
    int c = t & 63, isub = t >> 6;
    float acc[8] = {0,0,0,0,0,0,0,0};
    for (int jt = zs*2; jt < zs*2+2; jt++){
        __syncthreads();
        for (int ix = t; ix < 128*40; ix += 256){
            int jj = ix / 40, cc = ix % 40;
            int j = jt*128 + jj;
            wlds[jj][cc] = (cc < 16) ? proj[(size_t)j*1152 + 384 + h*16 + cc]
                                     : vpg[(size_t)j*288 + h*24 + (cc - 16)];
        }
        for (int ix = t; ix < 32*128; ix += 256){
            int rr = ix >> 7, jj = ix & 127;
            plds[rr][jj] = att[(size_t)(it*32 + rr)*NN + jt*128 + jj];
        }
        __syncthreads();
        if (c < 40){
            for (int jj = 0; jj < 128; jj += 4){
                float w0 = wlds[jj][c], w1 = wlds[jj+1][c], w2 = wlds[jj+2][c], w3 = wlds[jj+3][c];
                #pragma unroll
                for (int rr = 0; rr < 8; rr++){
                    floatx4 pv = *(floatx4*)&plds[isub*8+rr][jj];
                    acc[rr] += pv[0]*w0 + pv[1]*w1 + pv[2]*w2 + pv[3]*w3;
                }
            }
        }
    }
    if (c < 40){
        float* ocat = ws + OFF_OCAT;
        int col = (c < 16) ? (h*16 + c) : (576 + h*24 + (c - 16));
        for (int rr = 0; rr < 8; rr++){
            int i = it*32 + isub*8 + rr;
            atomicAdd(&ocat[(size_t)i*960 + col], acc[rr]);
        }
    }
}

// ---- K6: o_pair, 384 threads, one (h,c) per thread
__global__ __launch_bounds__(384) void k_opair(const int* __restrict__ idx, float* __restrict__ ws){
    __shared__ float pzlds[128][33];
    __shared__ float plds[12][132];
    int i = blockIdx.x, t = threadIdx.x;
    int ires = idx[i];
    const float* pz  = ws + OFF_PZ;
    const float* att = ws + OFF_ATT;
    int h = t >> 5, c = t & 31;
    float acc = 0.f;
    for (int jt = 0; jt < 6; jt++){
        __syncthreads();
        for (int ix = t; ix < 128*32; ix += 384){
            int jj = ix >> 5, cc = ix & 31;
            int jres = idx[jt*128 + jj];
            pzlds[jj][cc] = pz[((size_t)ires*NN + jres)*32 + cc];
        }
        for (int ix = t; ix < 12*128; ix += 384){
            int hh = ix / 128, jj = ix & 127;
            plds[hh][jj] = att[(size_t)hh*NSQ + (size_t)i*NN + jt*128 + jj];
        }
        __syncthreads();
        for (int jj = 0; jj < 128; jj += 4){
            floatx4 pv = *(floatx4*)&plds[h][jj];
            acc += pv[0]*pzlds[jj][c] + pv[1]*pzlds[jj+1][c] + pv[2]*pzlds[jj+2][c] + pv[3]*pzlds[jj+3][c];
        }
    }
    float* oc = ws + OFF_OCAT + (size_t)i*960 + 192;
    oc[h*32 + c] = acc;
}

// ---- K6b: o_pt local frame + norms
__global__ __launch_bounds__(96) void k_ptfin(const float* __restrict__ rot, const float* __restrict__ trans,
                                              float* __restrict__ ws){
    int i = blockIdx.x, p = threadIdx.x;
    float* base = ws + OFF_OCAT + (size_t)i*960;
    float* pt = base + 576 + p*3;
    float x = pt[0] - trans[i*3+0];
    float y = pt[1] - trans[i*3+1];
    float z = pt[2] - trans[i*3+2];
    const float* R = rot + (size_t)i*9;
    float lx = R[0]*x + R[3]*y + R[6]*z;
    float ly = R[1]*x + R[4]*y + R[7]*z;
    float lz = R[2]*x + R[5]*y + R[8]*z;
    pt[0] = lx; pt[1] = ly; pt[2] = lz;
    base[864 + p] = sqrtf(lx*lx + ly*ly + lz*lz + EPS_);
}

// ---- K7: final GEMM, k-split x4
__global__ __launch_bounds__(256) void k_out(const float* __restrict__ Wout, const float* __restrict__ Woutb,
                                             const float* __restrict__ Woutp, float* __restrict__ ws){
    __shared__ float olds[32][244];
    int it = blockIdx.x, ct = blockIdx.y, kc = blockIdx.z, t = threadIdx.x;
    const float* ocat = ws + OFF_OCAT;
    for (int ix = t; ix < 32*240; ix += 256){
        int r = ix / 240, kk = ix % 240;
        olds[r][kk] = ocat[(size_t)(it*32 + r)*960 + kc*240 + kk];
    }
    __syncthreads();
    int c = ct*128 + (t & 127);
    int ig = t >> 7;
    float acc[16] = {0,0,0,0,0,0,0,0,0,0,0,0,0,0,0,0};
    for (int kk = 0; kk < 240; kk += 4){
        float wv[4];
        #pragma unroll
        for (int jj = 0; jj < 4; jj++){
            int k = kc*240 + kk + jj;
            const float* wrow = (k < 192) ? (Wout  + (size_t)k*CS)
                              : (k < 576) ? (Woutb + (size_t)(k-192)*CS)
                                          : (Woutp + (size_t)(k-576)*CS);
            wv[jj] = wrow[c];
        }
        #pragma unroll
        for (int r = 0; r < 16; r++){
            floatx4 ov = *(floatx4*)&olds[ig*16 + r][kk];
            acc[r] += ov[0]*wv[0] + ov[1]*wv[1] + ov[2]*wv[2] + ov[3]*wv[3];
        }
    }
    float* psum = ws + OFF_PSUM + (size_t)kc*(768*384);
    for (int r = 0; r < 16; r++){
        int i = it*32 + ig*16 + r;
        psum[(size_t)i*CS + c] = acc[r];
    }
}

// ---- K7b: reduce psum -> out
__global__ __launch_bounds__(256) void k_red(const float* __restrict__ ws, float* __restrict__ out){
    int e = blockIdx.x*256 + threadIdx.x;
    const float* ps = ws + OFF_PSUM;
    out[e] = ps[e] + ps[294912 + e] + ps[2*294912 + e] + ps[3*294912 + e];
}

extern "C" void kernel_launch(void* const* d_in, const int* in_sizes, int n_in,
                              void* d_out, int out_size, void* d_ws, size_t ws_size,
                              hipStream_t stream){
    const float* s     = (const float*)d_in[0];
    const float* z     = (const float*)d_in[1];
    const float* rot   = (const float*)d_in[2];
    const float* trans = (const float*)d_in[3];
    const float* smask = (const float*)d_in[4];
    const float* gs    = (const float*)d_in[5];
    const float* bs    = (const float*)d_in[6];
    const float* gz    = (const float*)d_in[7];
    const float* bz    = (const float*)d_in[8];
    const float* Wq    = (const float*)d_in[9];
    const float* Wk    = (const float*)d_in[10];
    const float* Wv    = (const float*)d_in[11];
    const float* Wqp   = (const float*)d_in[12];
    const float* Wkp   = (const float*)d_in[13];
    const float* Wvp   = (const float*)d_in[14];
    const float* Wb    = (const float*)d_in[15];
    const float* Wdz   = (const float*)d_in[16];
    const float* hwin  = (const float*)d_in[17];
    const float* Wout  = (const float*)d_in[18];
    const float* Woutb = (const float*)d_in[19];
    const float* Woutp = (const float*)d_in[20];
    const int*   idx   = (const int*)d_in[21];
    float* ws  = (float*)d_ws;
    float* out = (float*)d_out;

    k_prep   <<<49, 128, 0, stream>>>(Wb, Wdz, hwin, ws);
    k_zero   <<<2880, 256, 0, stream>>>(ws);
    k_lns    <<<768, 128, 0, stream>>>(s, gs, bs, ws);
    k_proj   <<<dim3(48, 9), 256, 0, stream>>>(Wq, Wk, Wv, Wqp, Wkp, Wvp, ws);
    k_pts    <<<768, 192, 0, stream>>>(rot, trans, ws);
    k_z      <<<9216, 256, 0, stream>>>(z, gz, bz, ws);
    k_logits <<<dim3(96, 24), 256, 0, stream>>>(smask, idx, ws);
    k_softmax<<<9216, 192, 0, stream>>>(ws);
    k_ov     <<<dim3(12, 24, 3), 256, 0, stream>>>(ws);
    k_opair  <<<768, 384, 0, stream>>>(idx, ws);
    k_ptfin  <<<768, 96, 0, stream>>>(rot, trans, ws);
    k_out    <<<dim3(24, 3, 4), 256, 0, stream>>>(Wout, Woutb, Woutp, ws);
    k_red    <<<1152, 256, 0, stream>>>(ws, out);
}